// Round 2
// baseline (416.030 us; speedup 1.0000x reference)
//
#include <hip/hip_runtime.h>
#include <math.h>
#include <stdint.h>

// Problem shape (fixed by setup_inputs): P=512, R=256, S=256, K=3, threshold=0.
#define Pn 512
#define Rn 256
#define Sn 256

typedef unsigned long long u64;
typedef unsigned int u32;

// ---- u64 key machinery (proven): larger key == larger value, ties broken
// toward smaller index (lax.top_k semantics). ----
__device__ __forceinline__ u32 mono(float f) {
  u32 u = __float_as_uint(f);
  return (u & 0x80000000u) ? ~u : (u | 0x80000000u);
}
__device__ __forceinline__ float unmono(u32 m) {
  u32 bits = (m & 0x80000000u) ? (m & 0x7FFFFFFFu) : ~m;
  return __uint_as_float(bits);
}
__device__ __forceinline__ u64 makekey(float v, int idx) {
  return ((u64)mono(v) << 32) | (u32)(~(u32)idx);
}
__device__ __forceinline__ int key_idx(u64 k) { return (int)(~(u32)k); }
__device__ __forceinline__ float key_val(u64 k) { return unmono((u32)(k >> 32)); }

// ---- branchless float top-3 insert (proven). Strict >, ascending visit
// order => smaller index wins ties = lax.top_k semantics. ----
__device__ __forceinline__ void ins3f(float v, int i,
    float& t0, int& i0, float& t1, int& i1, float& t2, int& i2) {
  const bool b0 = v > t0, b1 = v > t1, b2 = v > t2;
  const float nt0 = b0 ? v : t0;
  const int   ni0 = b0 ? i : i0;
  const float nt1 = b0 ? t0 : (b1 ? v : t1);
  const int   ni1 = b0 ? i0 : (b1 ? i : i1);
  const float nt2 = b1 ? t1 : (b2 ? v : t2);
  const int   ni2 = b1 ? i1 : (b2 ? i : i2);
  t0 = nt0; i0 = ni0; t1 = nt1; i1 = ni1; t2 = nt2; i2 = ni2;
}

// branchless key top-3 insert (total order on u64 keys).
__device__ __forceinline__ void ins3k(u64 k, u64& k0, u64& k1, u64& k2) {
  const bool b0 = k > k0, b1 = k > k1, b2 = k > k2;
  const u64 n0 = b0 ? k : k0;
  const u64 n1 = b0 ? k0 : (b1 ? k : k1);
  const u64 n2 = b1 ? k1 : (b2 ? k : k2);
  k0 = n0; k1 = n1; k2 = n2;
}

__device__ __forceinline__ void compute_elem(
    int s, int r, bool rmask, int sm,
    float rv0, float rv1, float rv2, int ri0, int ri1, int ri2,
    float a0, int b0, float a1, int b1, float a2, int b2,
    float& oscore, float& ocorr) {
  const float rv = (s == ri0) ? rv0 : (s == ri1) ? rv1 : (s == ri2) ? rv2 : 0.0f;
  const float sv = (r == b0) ? a0 : (r == b1) ? a1 : (r == b2) ? a2 : 0.0f;
  oscore = 0.5f * (rv + sv);
  const bool m = rmask && (sm != 0);
  ocorr = (((rv > 0.0f) || (sv > 0.0f)) && m) ? 1.0f : 0.0f;
}

#define CHUNK 32
#define TSTRIDE 257  // odd stride -> all LDS patterns <=2-way bank alias (free)

// Single fused kernel: one block per p. Everything for image p stays on-CU.
//  Phase A (8 chunks of 32 rows): stage rows to LDS + per-thread column
//    top-3 scan (registers); 8 threads/row scan from LDS -> per-row partials
//    -> merged row top-3, exp'd into LDS (rowv/rowi).
//  Phase B: column top-3 exp'd into LDS (colvs/colis).
//  Phase C: dense write of both output maps straight from LDS tops.
// No workspace, no second kernel, no chip-wide barrier between tops & write.
__global__ __launch_bounds__(256) void fused_kernel(
    const float* __restrict__ score,
    const int* __restrict__ rmaskp, const int* __restrict__ smaskp,
    float* __restrict__ out) {
  __shared__ float tile[CHUNK * TSTRIDE];   // 32,896 B
  __shared__ u64   pk[8 * CHUNK * 3];       //  6,144 B
  __shared__ float rowv[Rn * 3];            //  3,072 B (exp'd row top vals)
  __shared__ int   rowi[Rn * 3];            //  3,072 B
  __shared__ float colvs[Sn * 3];           //  3,072 B (exp'd col top vals)
  __shared__ int   colis[Sn * 3];           //  3,072 B
  __shared__ int   rmk[Rn];                 //  1,024 B

  const int p  = blockIdx.x;
  const int s  = threadIdx.x;        // column 0..255
  const int rr = threadIdx.x & 31;   // row-in-chunk for the row scan
  const int q  = threadIdx.x >> 5;   // 8 col-quarters of 32
  const float* base = score + (size_t)p * (Rn * Sn) + s;

  rmk[s] = rmaskp[p * Rn + s];       // Rn == blockDim.x == 256, coalesced

  float t0 = -INFINITY, t1 = -INFINITY, t2 = -INFINITY;
  int   i0 = -1, i1 = -1, i2 = -1;

  for (int c = 0; c < 8; ++c) {
    const int r0 = c * CHUNK;
    // Stage chunk + column scan. Wave access per row = 256B contiguous
    // (coalesced); LDS writes lane-consecutive (conflict-free).
    #pragma unroll 16
    for (int r = 0; r < CHUNK; ++r) {
      const float v = base[(size_t)(r0 + r) * Sn];
      tile[r * TSTRIDE + s] = v;
      ins3f(v, r0 + r, t0, i0, t1, i1, t2, i2);
    }
    __syncthreads();
    // Row scan: thread (rr,q) scans cols q*32..q*32+31 of row r0+rr.
    // addr = rr*257 + cb + j: (257%32==1) -> 2-way alias = free.
    u64 k0 = 0, k1 = 0, k2 = 0;
    const int cb = q * 32;
    #pragma unroll 8
    for (int j = 0; j < 32; ++j)
      ins3k(makekey(tile[rr * TSTRIDE + cb + j], cb + j), k0, k1, k2);
    pk[(q * CHUNK + rr) * 3 + 0] = k0;
    pk[(q * CHUNK + rr) * 3 + 1] = k1;
    pk[(q * CHUNK + rr) * 3 + 2] = k2;
    __syncthreads();
    // Merge the 8 quarter-partials per row; threads 0..31 (one per row).
    // Row tops are exp'd ONCE here, straight into LDS.
    if (threadIdx.x < 32) {
      u64 m0 = pk[threadIdx.x * 3 + 0];
      u64 m1 = pk[threadIdx.x * 3 + 1];
      u64 m2 = pk[threadIdx.x * 3 + 2];
      #pragma unroll
      for (int qq = 1; qq < 8; ++qq) {
        #pragma unroll
        for (int kk = 0; kk < 3; ++kk)
          ins3k(pk[(qq * CHUNK + threadIdx.x) * 3 + kk], m0, m1, m2);
      }
      const int r = r0 + threadIdx.x;
      rowv[r * 3 + 0] = expf(key_val(m0)); rowi[r * 3 + 0] = key_idx(m0);
      rowv[r * 3 + 1] = expf(key_val(m1)); rowi[r * 3 + 1] = key_idx(m1);
      rowv[r * 3 + 2] = expf(key_val(m2)); rowi[r * 3 + 2] = key_idx(m2);
    }
    __syncthreads();  // pk/tile safe to overwrite next chunk
  }

  // Phase B: column tops (complete), exp'd into LDS.
  colvs[s * 3 + 0] = expf(t0); colis[s * 3 + 0] = i0;
  colvs[s * 3 + 1] = expf(t1); colis[s * 3 + 1] = i1;
  colvs[s * 3 + 2] = expf(t2); colis[s * 3 + 2] = i2;
  __syncthreads();

  // Phase C: dense streaming write of both maps. Warp per row-group,
  // 4 cols/lane, float4 stores. All top data from LDS (row reads are
  // wave-uniform -> broadcast; col reads one-time).
  const int warp  = threadIdx.x >> 6;
  const int lane  = threadIdx.x & 63;
  const int sbase = lane * 4;
  const size_t N  = (size_t)Pn * Rn * Sn;
  float* outp = out + (size_t)p * (Rn * Sn);

  const int4 sm = reinterpret_cast<const int4*>(smaskp + (size_t)p * Sn)[lane];

  float A0x, A0y, A0z, A0w, A1x, A1y, A1z, A1w, A2x, A2y, A2z, A2w;
  int   B0x, B0y, B0z, B0w, B1x, B1y, B1z, B1w, B2x, B2y, B2z, B2w;
  A0x = colvs[(sbase + 0) * 3 + 0]; B0x = colis[(sbase + 0) * 3 + 0];
  A1x = colvs[(sbase + 0) * 3 + 1]; B1x = colis[(sbase + 0) * 3 + 1];
  A2x = colvs[(sbase + 0) * 3 + 2]; B2x = colis[(sbase + 0) * 3 + 2];
  A0y = colvs[(sbase + 1) * 3 + 0]; B0y = colis[(sbase + 1) * 3 + 0];
  A1y = colvs[(sbase + 1) * 3 + 1]; B1y = colis[(sbase + 1) * 3 + 1];
  A2y = colvs[(sbase + 1) * 3 + 2]; B2y = colis[(sbase + 1) * 3 + 2];
  A0z = colvs[(sbase + 2) * 3 + 0]; B0z = colis[(sbase + 2) * 3 + 0];
  A1z = colvs[(sbase + 2) * 3 + 1]; B1z = colis[(sbase + 2) * 3 + 1];
  A2z = colvs[(sbase + 2) * 3 + 2]; B2z = colis[(sbase + 2) * 3 + 2];
  A0w = colvs[(sbase + 3) * 3 + 0]; B0w = colis[(sbase + 3) * 3 + 0];
  A1w = colvs[(sbase + 3) * 3 + 1]; B1w = colis[(sbase + 3) * 3 + 1];
  A2w = colvs[(sbase + 3) * 3 + 2]; B2w = colis[(sbase + 3) * 3 + 2];

  #pragma unroll 4
  for (int it = 0; it < 64; ++it) {
    const int r = it * 4 + warp;
    const float rv0 = rowv[r * 3 + 0], rv1 = rowv[r * 3 + 1], rv2 = rowv[r * 3 + 2];
    const int   ri0 = rowi[r * 3 + 0], ri1 = rowi[r * 3 + 1], ri2 = rowi[r * 3 + 2];
    const bool  rm  = rmk[r] != 0;

    float4 osc, oco;
    compute_elem(sbase + 0, r, rm, sm.x, rv0, rv1, rv2, ri0, ri1, ri2,
                 A0x, B0x, A1x, B1x, A2x, B2x, osc.x, oco.x);
    compute_elem(sbase + 1, r, rm, sm.y, rv0, rv1, rv2, ri0, ri1, ri2,
                 A0y, B0y, A1y, B1y, A2y, B2y, osc.y, oco.y);
    compute_elem(sbase + 2, r, rm, sm.z, rv0, rv1, rv2, ri0, ri1, ri2,
                 A0z, B0z, A1z, B1z, A2z, B2z, osc.z, oco.z);
    compute_elem(sbase + 3, r, rm, sm.w, rv0, rv1, rv2, ri0, ri1, ri2,
                 A0w, B0w, A1w, B1w, A2w, B2w, osc.w, oco.w);

    reinterpret_cast<float4*>(outp + (size_t)r * Sn)[lane]     = osc;
    reinterpret_cast<float4*>(outp + N + (size_t)r * Sn)[lane] = oco;
  }
}

extern "C" void kernel_launch(void* const* d_in, const int* in_sizes, int n_in,
                              void* d_out, int out_size, void* d_ws, size_t ws_size,
                              hipStream_t stream) {
  const float* score = (const float*)d_in[0];
  // d_in[1] = node_corr_scores: unused (conditional=False in reference)
  const int* rmask = (const int*)d_in[2];
  const int* smask = (const int*)d_in[3];
  float* out = (float*)d_out;
  (void)d_ws; (void)ws_size;  // no workspace needed anymore

  fused_kernel<<<Pn, 256, 0, stream>>>(score, rmask, smask, out);
}